// Round 1
// baseline (313.543 us; speedup 1.0000x reference)
//
#include <hip/hip_runtime.h>
#include <cstddef>

// Problem constants (from reference): x (16,4096,256) fp32, kernels (512,256) fp32.
#define BSZ 16
#define PN  4096
#define DD  256
#define CC  512

// GEMM tile config
#define TP 128          // positions per block
#define TC 128          // channels per block
#define BK 32           // K chunk
#define NPT (PN / TP)   // 32 position tiles
#define LDA (TP + 4)    // padded LDS leading dim (keeps 16B alignment, breaks pow2 conflicts)

// ---------------------------------------------------------------------------
// Kernel 1: zero the output (harness poisons d_out with 0xAA before every run)
// ---------------------------------------------------------------------------
__global__ __launch_bounds__(256) void zero_out_kernel(float4* __restrict__ out) {
    size_t i = (size_t)blockIdx.x * blockDim.x + threadIdx.x;
    out[i] = make_float4(0.f, 0.f, 0.f, 0.f);
}

// ---------------------------------------------------------------------------
// Kernel 2: fused fp32 score GEMM + per-column (max, argmax) over the p-tile.
// Block computes S[128p][128c] = X_tile(128x256) * K_tile(256x128)^T, relu,
// then column-reduces to one (max,idx) partial per channel, written to ws.
// Tie-breaking: strictly-greater updates + ascending iteration order keeps the
// FIRST occurrence of the max (matches jnp.argmax).
// ---------------------------------------------------------------------------
__global__ __launch_bounds__(256) void score_argmax_kernel(
    const float* __restrict__ x, const float* __restrict__ kern,
    float* __restrict__ pmax, int* __restrict__ pidx) {

    __shared__ float As[BK * LDA];
    __shared__ float Bs[BK * LDA];
    __shared__ float redv[16][TC];
    __shared__ int   redi[16][TC];

    const int ct = blockIdx.x;   // channel tile (0..3)
    const int pt = blockIdx.y;   // position tile (0..31)
    const int b  = blockIdx.z;   // batch (0..15)

    const int tid = threadIdx.x;
    const int tx  = tid & 15;    // 0..15 -> 8 channels each
    const int ty  = tid >> 4;    // 0..15 -> 8 positions each

    const int p0 = pt * TP;
    const int c0 = ct * TC;

    const float* xb = x    + ((size_t)b * PN + p0) * DD;
    const float* kb = kern + (size_t)c0 * DD;

    float acc[8][8];
#pragma unroll
    for (int i = 0; i < 8; i++)
#pragma unroll
        for (int j = 0; j < 8; j++) acc[i][j] = 0.f;

    for (int kk = 0; kk < DD; kk += BK) {
        // ---- stage X tile (128 x 32) and K tile (128 x 32), transposed in LDS
#pragma unroll
        for (int i = 0; i < 4; i++) {
            int fid = tid + i * 256;       // 0..1023
            int r   = fid >> 3;            // row 0..127
            int k4  = (fid & 7) * 4;       // k offset 0,4,..,28
            float4 av = *(const float4*)(xb + (size_t)r * DD + kk + k4);
            float4 bv = *(const float4*)(kb + (size_t)r * DD + kk + k4);
            As[(k4 + 0) * LDA + r] = av.x;
            As[(k4 + 1) * LDA + r] = av.y;
            As[(k4 + 2) * LDA + r] = av.z;
            As[(k4 + 3) * LDA + r] = av.w;
            Bs[(k4 + 0) * LDA + r] = bv.x;
            Bs[(k4 + 1) * LDA + r] = bv.y;
            Bs[(k4 + 2) * LDA + r] = bv.z;
            Bs[(k4 + 3) * LDA + r] = bv.w;
        }
        __syncthreads();

#pragma unroll
        for (int k = 0; k < BK; k++) {
            float4 a0 = *(const float4*)&As[k * LDA + ty * 8];
            float4 a1 = *(const float4*)&As[k * LDA + ty * 8 + 4];
            float4 b0 = *(const float4*)&Bs[k * LDA + tx * 8];
            float4 b1 = *(const float4*)&Bs[k * LDA + tx * 8 + 4];
            float a[8] = {a0.x, a0.y, a0.z, a0.w, a1.x, a1.y, a1.z, a1.w};
            float bb[8] = {b0.x, b0.y, b0.z, b0.w, b1.x, b1.y, b1.z, b1.w};
#pragma unroll
            for (int i = 0; i < 8; i++)
#pragma unroll
                for (int j = 0; j < 8; j++)
                    acc[i][j] = fmaf(a[i], bb[j], acc[i][j]);
        }
        __syncthreads();
    }

    // ---- relu + per-thread column max over its 8 rows (ascending => first occ)
#pragma unroll
    for (int j = 0; j < 8; j++) {
        float v = -1.f; int mi = 0;
#pragma unroll
        for (int i = 0; i < 8; i++) {
            float s = acc[i][j];
            s = s > 0.f ? s : 0.f;   // relu (matters for all-<=0 tie case)
            if (s > v) { v = s; mi = i; }
        }
        redv[ty][tx * 8 + j] = v;
        redi[ty][tx * 8 + j] = ty * 8 + mi;
    }
    __syncthreads();

    // ---- cross-thread column reduction (ascending ty => smaller p wins ties)
    if (tid < TC) {
        float v = -1.f; int mi = 0;
#pragma unroll
        for (int t = 0; t < 16; t++) {
            float tv = redv[t][tid];
            int   ti = redi[t][tid];
            if (tv > v) { v = tv; mi = ti; }
        }
        int c = c0 + tid;
        size_t o = ((size_t)b * CC + c) * NPT + pt;
        pmax[o] = v;
        pidx[o] = p0 + mi;
    }
}

// ---------------------------------------------------------------------------
// Kernel 3: per-(b,c) reduce the 32 p-tile partials (first-occurrence ties),
// then scatter-add kernels[c,:] into out[b, idx, :] with atomics (collisions
// between channels picking the same position are possible).
// ---------------------------------------------------------------------------
__global__ __launch_bounds__(64) void reduce_scatter_kernel(
    const float* __restrict__ pmax, const int* __restrict__ pidx,
    const float* __restrict__ kern, float* __restrict__ out) {

    const int c = blockIdx.x;
    const int b = blockIdx.y;
    const int l = threadIdx.x;

    float v = -1.f;
    int idx = 0x7fffffff;
    if (l < NPT) {
        size_t o = ((size_t)b * CC + c) * NPT + l;
        v   = pmax[o];
        idx = pidx[o];
    }
    // wave64 reduction; relu scores are >= 0 so sentinel -1 never wins
#pragma unroll
    for (int off = 32; off > 0; off >>= 1) {
        float ov = __shfl_down(v, off, 64);
        int   oi = __shfl_down(idx, off, 64);
        if (ov > v || (ov == v && oi < idx)) { v = ov; idx = oi; }
    }
    idx = __shfl(idx, 0, 64);

    float*       dst = out  + ((size_t)b * PN + idx) * DD;
    const float* src = kern + (size_t)c * DD;
#pragma unroll
    for (int d = l; d < DD; d += 64)
        atomicAdd(&dst[d], src[d]);
}

// ---------------------------------------------------------------------------
extern "C" void kernel_launch(void* const* d_in, const int* in_sizes, int n_in,
                              void* d_out, int out_size, void* d_ws, size_t ws_size,
                              hipStream_t stream) {
    const float* x    = (const float*)d_in[0];   // (16,4096,256)
    const float* kern = (const float*)d_in[1];   // (512,256)
    float* out = (float*)d_out;                  // (16,4096,256)

    // workspace: pmax [16][512][32] f32, pidx [16][512][32] i32  (2 MB total)
    float* pmax = (float*)d_ws;
    int*   pidx = (int*)((char*)d_ws + (size_t)BSZ * CC * NPT * sizeof(float));

    // 1) zero output: 16M floats = 4M float4
    zero_out_kernel<<<(BSZ * PN * DD) / 4 / 256, 256, 0, stream>>>((float4*)out);

    // 2) fused score GEMM + per-tile argmax partials
    score_argmax_kernel<<<dim3(CC / TC, PN / TP, BSZ), 256, 0, stream>>>(
        x, kern, pmax, pidx);

    // 3) final argmax reduce + scatter-add
    reduce_scatter_kernel<<<dim3(CC, BSZ), 64, 0, stream>>>(pmax, pidx, kern, out);
}

// Round 2
// 225.844 us; speedup vs baseline: 1.3883x; 1.3883x over previous
//
#include <hip/hip_runtime.h>
#include <cstddef>
#include <cstdint>

// x (16,4096,256) fp32, kernels (512,256) fp32, out (16,4096,256) fp32
#define BSZ 16
#define PN  4096
#define DD  256
#define CC  512
#define TP  128
#define TC  128
#define BK  32
#define NPT (PN / TP)   // 32 position tiles
#define LDK 40          // padded bf16 K-stride (80 B rows: 16B-aligned frags, conflict-light)

typedef short bf16x8 __attribute__((ext_vector_type(8)));
typedef float f32x4  __attribute__((ext_vector_type(4)));

struct Top2 { float v1, v2; int i1, i2; };

// comparator: larger value wins; tie -> smaller index (jnp.argmax first-occurrence)
__device__ __forceinline__ void t2_insert(Top2& t, float v, int i) {
  if (v > t.v1 || (v == t.v1 && i < t.i1)) {
    t.v2 = t.v1; t.i2 = t.i1; t.v1 = v; t.i1 = i;
  } else if (v > t.v2 || (v == t.v2 && i < t.i2)) {
    t.v2 = v; t.i2 = i;
  }
}

// split float4 -> packed bf16 hi (truncate) + bf16 lo (truncate of exact residual).
// x = hi + lo to ~2^-16 relative; one v_perm packs two hi-halves per pair.
__device__ __forceinline__ void split4(float4 v, uint2& hp, uint2& lp) {
  uint32_t u0 = __float_as_uint(v.x), u1 = __float_as_uint(v.y),
           u2 = __float_as_uint(v.z), u3 = __float_as_uint(v.w);
  float l0 = v.x - __uint_as_float(u0 & 0xffff0000u);   // exact residual
  float l1 = v.y - __uint_as_float(u1 & 0xffff0000u);
  float l2 = v.z - __uint_as_float(u2 & 0xffff0000u);
  float l3 = v.w - __uint_as_float(u3 & 0xffff0000u);
  hp.x = __builtin_amdgcn_perm(u1, u0, 0x07060302u);    // [bf16(y)|bf16(x)]
  hp.y = __builtin_amdgcn_perm(u3, u2, 0x07060302u);
  lp.x = __builtin_amdgcn_perm(__float_as_uint(l1), __float_as_uint(l0), 0x07060302u);
  lp.y = __builtin_amdgcn_perm(__float_as_uint(l3), __float_as_uint(l2), 0x07060302u);
}

// ---------------------------------------------------------------------------
// Pre-convert kernels (512x256) to bf16 hi/lo once (saves per-block VALU work)
// ---------------------------------------------------------------------------
__global__ __launch_bounds__(256) void convert_kern_kernel(
    const float* __restrict__ kern, uint2* __restrict__ kh, uint2* __restrict__ kl) {
  int i = blockIdx.x * 256 + threadIdx.x;   // one float4 each, 32768 total
  float4 v = ((const float4*)kern)[i];
  uint2 hp, lp; split4(v, hp, lp);
  kh[i] = hp; kl[i] = lp;
}

// ---------------------------------------------------------------------------
// Fused split-bf16 MFMA score GEMM + per-column top-2 over the 128-p tile.
// Block: 128p x 128c, 4 waves in 2x2, each wave 64x64 via 4x4 16x16x32 frags.
// 3 pairings (Ah*Bh + Ah*Bl + Al*Bh) accumulate into one fp32 accumulator.
// ---------------------------------------------------------------------------
__global__ __launch_bounds__(256) void score_kernel(
    const float* __restrict__ x, const short* __restrict__ khs, const short* __restrict__ kls,
    float2* __restrict__ pv2, uint32_t* __restrict__ pix) {

  __shared__ __align__(16) short lds[4 * TP * LDK];   // 40 KB: As_h|As_l|Bs_h|Bs_l
  short* As_h = lds;
  short* As_l = lds + TP * LDK;
  short* Bs_h = lds + 2 * TP * LDK;
  short* Bs_l = lds + 3 * TP * LDK;

  const int ct = blockIdx.x, pt = blockIdx.y, b = blockIdx.z;
  const int tid  = threadIdx.x;
  const int lane = tid & 63, wave = tid >> 6;
  const int wr = wave >> 1, wc = wave & 1;   // 2x2 wave grid
  const int lr = lane & 15, kg = lane >> 4;  // fragment row/col, k-group

  const float* xb  = x   + ((size_t)b * PN + (size_t)pt * TP) * DD;
  const short* kbh = khs + (size_t)ct * TC * DD;
  const short* kbl = kls + (size_t)ct * TC * DD;

  f32x4 acc[4][4];
#pragma unroll
  for (int i = 0; i < 4; i++)
#pragma unroll
    for (int j = 0; j < 4; j++) acc[i][j] = (f32x4)0.f;

  for (int kk = 0; kk < DD; kk += BK) {
    // stage x chunk (128x32 fp32), converting to bf16 hi/lo in-register
#pragma unroll
    for (int i = 0; i < 4; i++) {
      int fid = tid + i * 256;            // 0..1023
      int r = fid >> 3, k4 = (fid & 7) * 4;
      float4 v = *(const float4*)(xb + (size_t)r * DD + kk + k4);
      uint2 hp, lp; split4(v, hp, lp);
      *(uint2*)&As_h[r * LDK + k4] = hp;
      *(uint2*)&As_l[r * LDK + k4] = lp;
    }
    // stage kern chunk (128x32 bf16 hi/lo, preconverted) — pure copy-through
#pragma unroll
    for (int i = 0; i < 2; i++) {
      int fid = tid + i * 256;            // 0..511
      int r = fid >> 2, k8 = (fid & 3) * 8;
      *(uint4*)&Bs_h[r * LDK + k8] = *(const uint4*)&kbh[(size_t)r * DD + kk + k8];
      *(uint4*)&Bs_l[r * LDK + k8] = *(const uint4*)&kbl[(size_t)r * DD + kk + k8];
    }
    __syncthreads();

    bf16x8 Ah[4], Al[4];
#pragma unroll
    for (int fp = 0; fp < 4; fp++) {
      int off = (wr * 64 + fp * 16 + lr) * LDK + kg * 8;
      Ah[fp] = *(const bf16x8*)&As_h[off];
      Al[fp] = *(const bf16x8*)&As_l[off];
    }
#pragma unroll
    for (int fc = 0; fc < 4; fc++) {
      int off = (wc * 64 + fc * 16 + lr) * LDK + kg * 8;
      bf16x8 Bh = *(const bf16x8*)&Bs_h[off];
      bf16x8 Bl = *(const bf16x8*)&Bs_l[off];
#pragma unroll
      for (int fp = 0; fp < 4; fp++) {
        acc[fp][fc] = __builtin_amdgcn_mfma_f32_16x16x32_bf16(Ah[fp], Bh, acc[fp][fc], 0, 0, 0);
        acc[fp][fc] = __builtin_amdgcn_mfma_f32_16x16x32_bf16(Ah[fp], Bl, acc[fp][fc], 0, 0, 0);
        acc[fp][fc] = __builtin_amdgcn_mfma_f32_16x16x32_bf16(Al[fp], Bh, acc[fp][fc], 0, 0, 0);
      }
    }
    __syncthreads();
  }

  // relu + per-lane top2 per column (D layout: col=lane&15, row=kg*4+reg)
  float4* scratch = (float4*)lds;   // reuse tile LDS: [slot 0..7][col 0..127]
  const int slot = wr * 4 + kg;
#pragma unroll
  for (int fc = 0; fc < 4; fc++) {
    Top2 t; t.v1 = -1.f; t.v2 = -1.f; t.i1 = 0x7fffffff; t.i2 = 0x7fffffff;
#pragma unroll
    for (int fp = 0; fp < 4; fp++)
#pragma unroll
      for (int r = 0; r < 4; r++) {
        float v = acc[fp][fc][r]; v = v > 0.f ? v : 0.f;
        t2_insert(t, v, wr * 64 + fp * 16 + kg * 4 + r);
      }
    int c_local = wc * 64 + fc * 16 + lr;
    scratch[slot * TC + c_local] =
        make_float4(t.v1, __int_as_float(t.i1), t.v2, __int_as_float(t.i2));
  }
  __syncthreads();

  // final per-column merge of 8 slots -> (v1,i1,v2,i2) partial for this p-tile
  if (tid < TC) {
    Top2 t; t.v1 = -1.f; t.v2 = -1.f; t.i1 = 0x7fffffff; t.i2 = 0x7fffffff;
#pragma unroll
    for (int s = 0; s < 8; s++) {
      float4 e = scratch[s * TC + tid];
      t2_insert(t, e.x, __float_as_int(e.y));
      t2_insert(t, e.z, __float_as_int(e.w));
    }
    int c = ct * TC + tid;
    size_t o = ((size_t)b * CC + c) * NPT + pt;
    uint32_t p1 = (uint32_t)(pt * TP + t.i1);
    uint32_t p2 = (uint32_t)(pt * TP + t.i2);
    pv2[o] = make_float2(t.v1, t.v2);
    pix[o] = (p1 << 16) | (p2 & 0xffffu);
  }
}

// ---------------------------------------------------------------------------
// Per-(b,c): merge 32 tile top-2s (butterfly), eps-guarded winner; if top-2
// within eps, recompute BOTH dots exactly in fp32 and compare. Then
// atomically scatter-add kernels[c,:] into out[b,winner,:].
// ---------------------------------------------------------------------------
__global__ __launch_bounds__(64) void reduce_scatter_kernel(
    const float2* __restrict__ pv2, const uint32_t* __restrict__ pix,
    const float* __restrict__ x, const float* __restrict__ kern,
    float* __restrict__ out) {
  const int c = blockIdx.x, b = blockIdx.y;
  const int l = threadIdx.x;

  Top2 t; t.v1 = -1.f; t.v2 = -1.f; t.i1 = 0x7fffffff; t.i2 = 0x7fffffff;
  if (l < NPT) {
    size_t o = ((size_t)b * CC + c) * NPT + l;
    float2 v = pv2[o]; uint32_t ii = pix[o];
    t.v1 = v.x; t.v2 = v.y; t.i1 = (int)(ii >> 16); t.i2 = (int)(ii & 0xffffu);
  }
  // butterfly top-2 merge across 64 lanes (disjoint subcubes -> no dup merges)
#pragma unroll
  for (int m = 1; m < 64; m <<= 1) {
    float uv1 = __shfl_xor(t.v1, m, 64);
    int   ui1 = __shfl_xor(t.i1, m, 64);
    float uv2 = __shfl_xor(t.v2, m, 64);
    int   ui2 = __shfl_xor(t.i2, m, 64);
    t2_insert(t, uv1, ui1);
    t2_insert(t, uv2, ui2);
  }

  int winner = t.i1;
  if (t.v1 - t.v2 <= 1e-4f * t.v1) {      // near-tie: exact fp32 rescue (rare)
    const float4* x1 = (const float4*)(x + ((size_t)b * PN + t.i1) * DD);
    const float4* x2 = (const float4*)(x + ((size_t)b * PN + t.i2) * DD);
    const float4* kc = (const float4*)(kern + (size_t)c * DD);
    float4 a1 = x1[l], a2 = x2[l], k4 = kc[l];
    float s1 = a1.x * k4.x + a1.y * k4.y + a1.z * k4.z + a1.w * k4.w;
    float s2 = a2.x * k4.x + a2.y * k4.y + a2.z * k4.z + a2.w * k4.w;
#pragma unroll
    for (int m = 1; m < 64; m <<= 1) {
      s1 += __shfl_xor(s1, m, 64);
      s2 += __shfl_xor(s2, m, 64);
    }
    s1 = fmaxf(s1, 0.f); s2 = fmaxf(s2, 0.f);
    if (s2 > s1 || (s2 == s1 && t.i2 < t.i1)) winner = t.i2;
  }

  float*       dst = out  + ((size_t)b * PN + winner) * DD;
  const float* src = kern + (size_t)c * DD;
#pragma unroll
  for (int d = 0; d < 4; d++)
    atomicAdd(&dst[l * 4 + d], src[l * 4 + d]);
}

// ---------------------------------------------------------------------------
extern "C" void kernel_launch(void* const* d_in, const int* in_sizes, int n_in,
                              void* d_out, int out_size, void* d_ws, size_t ws_size,
                              hipStream_t stream) {
  const float* x    = (const float*)d_in[0];   // (16,4096,256)
  const float* kern = (const float*)d_in[1];   // (512,256)
  float* out = (float*)d_out;

  // ws: pv2 2 MB | pix 1 MB | kh 256 KB | kl 256 KB  (3.5 MB total)
  char* ws = (char*)d_ws;
  float2*   pv2 = (float2*)ws;
  uint32_t* pix = (uint32_t*)(ws + (size_t)BSZ * CC * NPT * sizeof(float2));
  short*    khs = (short*)(ws + 3u * 1024 * 1024);
  short*    kls = (short*)(ws + 3u * 1024 * 1024 + 256u * 1024);

  hipMemsetAsync(d_out, 0, (size_t)BSZ * PN * DD * sizeof(float), stream);

  convert_kern_kernel<<<(CC * DD / 4) / 256, 256, 0, stream>>>(
      kern, (uint2*)khs, (uint2*)kls);

  score_kernel<<<dim3(CC / TC, PN / TP, BSZ), 256, 0, stream>>>(
      x, khs, kls, pv2, pix);

  reduce_scatter_kernel<<<dim3(CC, BSZ), 64, 0, stream>>>(
      pv2, pix, x, kern, out);
}

// Round 3
// 220.280 us; speedup vs baseline: 1.4234x; 1.0253x over previous
//
#include <hip/hip_runtime.h>
#include <cstddef>
#include <cstdint>

// x (16,4096,256) fp32, kernels (512,256) fp32, out (16,4096,256) fp32
#define BSZ 16
#define PN  4096
#define DD  256
#define CC  512
#define TP  128
#define TC  128
#define NPT (PN / TP)    // 32 position tiles
#define NKC 8            // 8 K-chunks of 32

typedef short bf16x8 __attribute__((ext_vector_type(8)));
typedef float f32x4  __attribute__((ext_vector_type(4)));

struct Top2 { float v1, v2; int i1, i2; };

// larger value wins; tie -> smaller index (jnp.argmax first-occurrence)
__device__ __forceinline__ void t2_insert(Top2& t, float v, int i) {
  if (v > t.v1 || (v == t.v1 && i < t.i1)) {
    t.v2 = t.v1; t.i2 = t.i1; t.v1 = v; t.i1 = i;
  } else if (v > t.v2 || (v == t.v2 && i < t.i2)) {
    t.v2 = v; t.i2 = i;
  }
}

// split float4 -> packed bf16 hi (truncate) + bf16 lo (truncate of exact residual)
__device__ __forceinline__ void split4(float4 v, uint2& hp, uint2& lp) {
  uint32_t u0 = __float_as_uint(v.x), u1 = __float_as_uint(v.y),
           u2 = __float_as_uint(v.z), u3 = __float_as_uint(v.w);
  float l0 = v.x - __uint_as_float(u0 & 0xffff0000u);
  float l1 = v.y - __uint_as_float(u1 & 0xffff0000u);
  float l2 = v.z - __uint_as_float(u2 & 0xffff0000u);
  float l3 = v.w - __uint_as_float(u3 & 0xffff0000u);
  hp.x = __builtin_amdgcn_perm(u1, u0, 0x07060302u);
  hp.y = __builtin_amdgcn_perm(u3, u2, 0x07060302u);
  lp.x = __builtin_amdgcn_perm(__float_as_uint(l1), __float_as_uint(l0), 0x07060302u);
  lp.y = __builtin_amdgcn_perm(__float_as_uint(l3), __float_as_uint(l2), 0x07060302u);
}

// async 16B global -> LDS (dest = wave-uniform base + lane*16)
__device__ __forceinline__ void gld16(const void* gsrc, void* ldst) {
  __builtin_amdgcn_global_load_lds(
      (const __attribute__((address_space(1))) unsigned int*)gsrc,
      (__attribute__((address_space(3))) unsigned int*)ldst, 16, 0, 0);
}

// ---------------------------------------------------------------------------
// convert x (fp32) -> bf16 hi/lo in MFMA-staging order, stored in d_out.
// Chunk (b,pt,kc) = 16 KB: hi[512 slots * 16B] | lo[512 slots * 16B],
// slot s = fp*64 + kg*16 + lr holds row fp*16+lr, k = kc*32 + kg*8 .. +8.
// ---------------------------------------------------------------------------
__global__ __launch_bounds__(256) void convert_x_kernel(
    const float* __restrict__ x, uint32_t* __restrict__ xs) {
  const int kc = blockIdx.x, pt = blockIdx.y, b = blockIdx.z;
  const size_t chunk = (((size_t)b * NPT + pt) * NKC + kc) * 4096;  // uints
#pragma unroll
  for (int s0 = 0; s0 < 2; s0++) {
    int s  = threadIdx.x + s0 * 256;          // slot 0..511
    int fp = s >> 6, kg = (s >> 4) & 3, lr = s & 15;
    int r  = fp * 16 + lr, k0 = kg * 8;
    const float* src = x + ((size_t)b * PN + (size_t)pt * TP + r) * DD + kc * 32 + k0;
    float4 v0 = *(const float4*)src, v1 = *(const float4*)(src + 4);
    uint2 h0, l0, h1, l1; split4(v0, h0, l0); split4(v1, h1, l1);
    *(uint4*)&xs[chunk + (size_t)s * 4]        = make_uint4(h0.x, h0.y, h1.x, h1.y);
    *(uint4*)&xs[chunk + 2048 + (size_t)s * 4] = make_uint4(l0.x, l0.y, l1.x, l1.y);
  }
}

// same for kernels (512x256): chunk (ct,kc), rows are channels ct*128+r
__global__ __launch_bounds__(256) void convert_k_kernel(
    const float* __restrict__ kern, uint32_t* __restrict__ ks) {
  const int kc = blockIdx.x, ct = blockIdx.y;
  const size_t chunk = ((size_t)ct * NKC + kc) * 4096;
#pragma unroll
  for (int s0 = 0; s0 < 2; s0++) {
    int s  = threadIdx.x + s0 * 256;
    int fp = s >> 6, kg = (s >> 4) & 3, lr = s & 15;
    int r  = fp * 16 + lr, k0 = kg * 8;
    const float* src = kern + ((size_t)ct * TC + r) * DD + kc * 32 + k0;
    float4 v0 = *(const float4*)src, v1 = *(const float4*)(src + 4);
    uint2 h0, l0, h1, l1; split4(v0, h0, l0); split4(v1, h1, l1);
    *(uint4*)&ks[chunk + (size_t)s * 4]        = make_uint4(h0.x, h0.y, h1.x, h1.y);
    *(uint4*)&ks[chunk + 2048 + (size_t)s * 4] = make_uint4(l0.x, l0.y, l1.x, l1.y);
  }
}

// ---------------------------------------------------------------------------
// Score GEMM: 128p x 128c per block, split-bf16 3-MFMA, async LDS staging,
// fused per-column top-2 over the p-tile.
// ---------------------------------------------------------------------------
__global__ __launch_bounds__(256) void score_kernel(
    const uint32_t* __restrict__ xs, const uint32_t* __restrict__ ks,
    float2* __restrict__ pv2, uint32_t* __restrict__ pix) {

  __shared__ __align__(16) short lds[2 * 8192];   // As 16KB | Bs 16KB
  short* As = lds;
  short* Bs = lds + 8192;

  const int ct = blockIdx.x, pt = blockIdx.y, b = blockIdx.z;
  const int tid  = threadIdx.x;
  const int lane = tid & 63, wave = tid >> 6;
  const int wr = wave >> 1, wc = wave & 1;
  const int lr = lane & 15, kg = lane >> 4;

  const char* xsb = (const char*)xs + (((size_t)b * NPT + pt) * NKC) * 16384;
  const char* ksb = (const char*)ks + ((size_t)ct * NKC) * 16384;

  f32x4 acc[4][4];
#pragma unroll
  for (int i = 0; i < 4; i++)
#pragma unroll
    for (int j = 0; j < 4; j++) acc[i][j] = (f32x4)0.f;

  for (int kc = 0; kc < NKC; kc++) {
    const char* asrc = xsb + kc * 16384 + tid * 16;
    const char* bsrc = ksb + kc * 16384 + tid * 16;
    char* adst = (char*)As + tid * 16;
    char* bdst = (char*)Bs + tid * 16;
#pragma unroll
    for (int i = 0; i < 4; i++) {
      gld16(asrc + i * 4096, adst + i * 4096);
      gld16(bsrc + i * 4096, bdst + i * 4096);
    }
    __syncthreads();   // drains vmcnt -> staged data visible

    bf16x8 Ah[4], Al[4];
    const int aoff = wr * 2048 + lane * 8;   // shorts; fp stride = 512 shorts
#pragma unroll
    for (int fp = 0; fp < 4; fp++) {
      Ah[fp] = *(const bf16x8*)&As[aoff + fp * 512];
      Al[fp] = *(const bf16x8*)&As[4096 + aoff + fp * 512];
    }
    const int boff = wc * 2048 + lane * 8;
#pragma unroll
    for (int fc = 0; fc < 4; fc++) {
      bf16x8 Bh = *(const bf16x8*)&Bs[boff + fc * 512];
      bf16x8 Bl = *(const bf16x8*)&Bs[4096 + boff + fc * 512];
#pragma unroll
      for (int fp = 0; fp < 4; fp++) {
        acc[fp][fc] = __builtin_amdgcn_mfma_f32_16x16x32_bf16(Ah[fp], Bh, acc[fp][fc], 0, 0, 0);
        acc[fp][fc] = __builtin_amdgcn_mfma_f32_16x16x32_bf16(Ah[fp], Bl, acc[fp][fc], 0, 0, 0);
        acc[fp][fc] = __builtin_amdgcn_mfma_f32_16x16x32_bf16(Al[fp], Bh, acc[fp][fc], 0, 0, 0);
      }
    }
    __syncthreads();   // all frag reads done before next chunk overwrites LDS
  }

  // relu + per-lane top2 per column (C layout: col=lane&15, row=kg*4+reg)
  float4* scratch = (float4*)lds;   // reuse: [slot 0..7][col 0..127]
  const int slot = wr * 4 + kg;
#pragma unroll
  for (int fc = 0; fc < 4; fc++) {
    Top2 t; t.v1 = -1.f; t.v2 = -1.f; t.i1 = 0x7fffffff; t.i2 = 0x7fffffff;
#pragma unroll
    for (int fp = 0; fp < 4; fp++)
#pragma unroll
      for (int r = 0; r < 4; r++) {
        float v = acc[fp][fc][r]; v = v > 0.f ? v : 0.f;
        t2_insert(t, v, wr * 64 + fp * 16 + kg * 4 + r);
      }
    int c_local = wc * 64 + fc * 16 + lr;
    scratch[slot * TC + c_local] =
        make_float4(t.v1, __int_as_float(t.i1), t.v2, __int_as_float(t.i2));
  }
  __syncthreads();

  if (tid < TC) {
    Top2 t; t.v1 = -1.f; t.v2 = -1.f; t.i1 = 0x7fffffff; t.i2 = 0x7fffffff;
#pragma unroll
    for (int s = 0; s < 8; s++) {
      float4 e = scratch[s * TC + tid];
      t2_insert(t, e.x, __float_as_int(e.y));
      t2_insert(t, e.z, __float_as_int(e.w));
    }
    int c = ct * TC + tid;
    size_t o = ((size_t)b * CC + c) * NPT + pt;
    uint32_t p1 = (uint32_t)(pt * TP + t.i1);
    uint32_t p2 = (uint32_t)(pt * TP + t.i2);
    pv2[o] = make_float2(t.v1, t.v2);
    pix[o] = (p1 << 16) | (p2 & 0xffffu);
  }
}

// ---------------------------------------------------------------------------
// Per-(b,c): merge 32 tile top-2s; eps-guarded winner; exact fp32 rescue of
// near-ties. Writes winner[b][c] only (no atomics, no scatter).
// ---------------------------------------------------------------------------
__global__ __launch_bounds__(64) void reduce_winner_kernel(
    const float2* __restrict__ pv2, const uint32_t* __restrict__ pix,
    const float* __restrict__ x, const float* __restrict__ kern,
    int* __restrict__ winner) {
  const int c = blockIdx.x, b = blockIdx.y;
  const int l = threadIdx.x;

  Top2 t; t.v1 = -1.f; t.v2 = -1.f; t.i1 = 0x7fffffff; t.i2 = 0x7fffffff;
  if (l < NPT) {
    size_t o = ((size_t)b * CC + c) * NPT + l;
    float2 v = pv2[o]; uint32_t ii = pix[o];
    t.v1 = v.x; t.v2 = v.y; t.i1 = (int)(ii >> 16); t.i2 = (int)(ii & 0xffffu);
  }
#pragma unroll
  for (int m = 1; m < 64; m <<= 1) {
    float uv1 = __shfl_xor(t.v1, m, 64);
    int   ui1 = __shfl_xor(t.i1, m, 64);
    float uv2 = __shfl_xor(t.v2, m, 64);
    int   ui2 = __shfl_xor(t.i2, m, 64);
    t2_insert(t, uv1, ui1);
    t2_insert(t, uv2, ui2);
  }

  int win = t.i1;
  // guard band: relative + absolute term covering worst-case dropped Al*Bl
  if (t.v1 - t.v2 <= 1e-4f * t.v1 + 1e-5f) {
    const float4* x1 = (const float4*)(x + ((size_t)b * PN + t.i1) * DD);
    const float4* x2 = (const float4*)(x + ((size_t)b * PN + t.i2) * DD);
    const float4* kc = (const float4*)(kern + (size_t)c * DD);
    float4 a1 = x1[l], a2 = x2[l], k4 = kc[l];
    float s1 = a1.x * k4.x + a1.y * k4.y + a1.z * k4.z + a1.w * k4.w;
    float s2 = a2.x * k4.x + a2.y * k4.y + a2.z * k4.z + a2.w * k4.w;
#pragma unroll
    for (int m = 1; m < 64; m <<= 1) {
      s1 += __shfl_xor(s1, m, 64);
      s2 += __shfl_xor(s2, m, 64);
    }
    s1 = fmaxf(s1, 0.f); s2 = fmaxf(s2, 0.f);
    if (s2 > s1 || (s2 == s1 && t.i2 < t.i1)) win = t.i2;
  }
  if (l == 0) winner[(size_t)b * CC + c] = win;
}

// ---------------------------------------------------------------------------
// One wave per (b,p): gather channels whose winner==p via ballot over the
// 512-entry winner row, sum their kernel rows, write the full output row.
// Covers every output element -> no memset, no atomics.
// ---------------------------------------------------------------------------
__global__ __launch_bounds__(64) void write_out_kernel(
    const int* __restrict__ winner, const float* __restrict__ kern,
    float4* __restrict__ out) {
  const int p = blockIdx.x, b = blockIdx.y;
  const int l = threadIdx.x;
  const int* wb = winner + (size_t)b * CC;

  int4 w0 = *(const int4*)&wb[l * 8];
  int4 w1 = *(const int4*)&wb[l * 8 + 4];
  int wv[8] = {w0.x, w0.y, w0.z, w0.w, w1.x, w1.y, w1.z, w1.w};

  float4 acc = make_float4(0.f, 0.f, 0.f, 0.f);
#pragma unroll
  for (int j = 0; j < 8; j++) {
    unsigned long long m = __ballot(wv[j] == p);
    while (m) {
      int bit = __ffsll((long long)m) - 1; m &= m - 1;
      int c = bit * 8 + j;                     // wave-uniform
      float4 kv = ((const float4*)(kern + (size_t)c * DD))[l];
      acc.x += kv.x; acc.y += kv.y; acc.z += kv.z; acc.w += kv.w;
    }
  }
  out[((size_t)b * PN + p) * 64 + l] = acc;
}

// ---------------------------------------------------------------------------
extern "C" void kernel_launch(void* const* d_in, const int* in_sizes, int n_in,
                              void* d_out, int out_size, void* d_ws, size_t ws_size,
                              hipStream_t stream) {
  const float* x    = (const float*)d_in[0];   // (16,4096,256)
  const float* kern = (const float*)d_in[1];   // (512,256)
  float* out = (float*)d_out;

  // d_out doubles as scratch for the staging-ordered bf16 hi/lo x (exactly
  // 67 MB); it is consumed by score_kernel and only then overwritten by
  // write_out_kernel.
  uint32_t* xs = (uint32_t*)d_out;

  // ws: pv2 2 MB | pix 1 MB | ks 512 KB | winner 32 KB
  char* ws = (char*)d_ws;
  float2*   pv2 = (float2*)ws;
  uint32_t* pix = (uint32_t*)(ws + (size_t)BSZ * CC * NPT * sizeof(float2));
  uint32_t* ks  = (uint32_t*)(ws + 3u * 1024 * 1024);
  int*      win = (int*)(ws + 3u * 1024 * 1024 + 512u * 1024);

  convert_k_kernel<<<dim3(NKC, CC / TC), 256, 0, stream>>>(kern, ks);
  convert_x_kernel<<<dim3(NKC, NPT, BSZ), 256, 0, stream>>>(x, xs);

  score_kernel<<<dim3(CC / TC, NPT, BSZ), 256, 0, stream>>>(xs, ks, pv2, pix);

  reduce_winner_kernel<<<dim3(CC, BSZ), 64, 0, stream>>>(pv2, pix, x, kern, win);

  write_out_kernel<<<dim3(PN, BSZ), 64, 0, stream>>>(win, kern, (float4*)out);
}

// Round 6
// 199.360 us; speedup vs baseline: 1.5727x; 1.1049x over previous
//
#include <hip/hip_runtime.h>
#include <cstddef>
#include <cstdint>

// x (16,4096,256) fp32, kernels (512,256) fp32, out (16,4096,256) fp32
#define BSZ 16
#define PN  4096
#define DD  256
#define CC  512
#define TP  128
#define TC  128
#define NPT (PN / TP)    // 32 position tiles
#define NKC 8            // 8 K-chunks of 32

typedef short bf16x8 __attribute__((ext_vector_type(8)));
typedef float f32x4  __attribute__((ext_vector_type(4)));

#define MEMFENCE() __asm__ __volatile__("" ::: "memory")
// s_waitcnt imm (gfx9/CDNA): vmcnt[3:0]=bits3:0, expcnt=bits6:4, lgkmcnt=bits12:8,
// vmcnt[5:4]=bits15:14. "Don't care" lgkm/exp = all-ones.
#define WAITCNT_VM8 0x1F78
#define WAITCNT_VM0 0x1F70

struct Top2 { float v1, v2; int i1, i2; };

// larger value wins; tie -> smaller index (jnp.argmax first-occurrence)
__device__ __forceinline__ void t2_insert(Top2& t, float v, int i) {
  if (v > t.v1 || (v == t.v1 && i < t.i1)) {
    t.v2 = t.v1; t.i2 = t.i1; t.v1 = v; t.i1 = i;
  } else if (v > t.v2 || (v == t.v2 && i < t.i2)) {
    t.v2 = v; t.i2 = i;
  }
}

// split float4 -> packed bf16 hi (truncate) + bf16 lo (truncate of exact residual)
__device__ __forceinline__ void split4(float4 v, uint2& hp, uint2& lp) {
  uint32_t u0 = __float_as_uint(v.x), u1 = __float_as_uint(v.y),
           u2 = __float_as_uint(v.z), u3 = __float_as_uint(v.w);
  float l0 = v.x - __uint_as_float(u0 & 0xffff0000u);
  float l1 = v.y - __uint_as_float(u1 & 0xffff0000u);
  float l2 = v.z - __uint_as_float(u2 & 0xffff0000u);
  float l3 = v.w - __uint_as_float(u3 & 0xffff0000u);
  hp.x = __builtin_amdgcn_perm(u1, u0, 0x07060302u);
  hp.y = __builtin_amdgcn_perm(u3, u2, 0x07060302u);
  lp.x = __builtin_amdgcn_perm(__float_as_uint(l1), __float_as_uint(l0), 0x07060302u);
  lp.y = __builtin_amdgcn_perm(__float_as_uint(l3), __float_as_uint(l2), 0x07060302u);
}

// async 16B global -> LDS (dest = wave-uniform base + lane*16; global addr free)
__device__ __forceinline__ void gld16(const void* gsrc, void* ldst) {
  __builtin_amdgcn_global_load_lds(
      (const __attribute__((address_space(1))) unsigned int*)gsrc,
      (__attribute__((address_space(3))) unsigned int*)ldst, 16, 0, 0);
}

// ---------------------------------------------------------------------------
// kernels (512x256) -> bf16 hi/lo in MFMA-staging slot order.
// Chunk (ct,kc) = 16 KB: hi[512 slots*16B] | lo[...]; slot s = fp*64+kg*16+lr
// holds channel row fp*16+lr, k = kc*32 + kg*8 .. +8.
// ---------------------------------------------------------------------------
__global__ __launch_bounds__(256) void convert_k_kernel(
    const float* __restrict__ kern, uint32_t* __restrict__ ks) {
  const int kc = blockIdx.x, ct = blockIdx.y;
  const size_t chunk = ((size_t)ct * NKC + kc) * 4096;
#pragma unroll
  for (int s0 = 0; s0 < 2; s0++) {
    int s  = threadIdx.x + s0 * 256;
    int fp = s >> 6, kg = (s >> 4) & 3, lr = s & 15;
    int r  = fp * 16 + lr, k0 = kg * 8;
    const float* src = kern + ((size_t)ct * TC + r) * DD + kc * 32 + k0;
    float4 v0 = *(const float4*)src, v1 = *(const float4*)(src + 4);
    uint2 h0, l0, h1, l1; split4(v0, h0, l0); split4(v1, h1, l1);
    *(uint4*)&ks[chunk + (size_t)s * 4]        = make_uint4(h0.x, h0.y, h1.x, h1.y);
    *(uint4*)&ks[chunk + 2048 + (size_t)s * 4] = make_uint4(l0.x, l0.y, l1.x, l1.y);
  }
}

// ---------------------------------------------------------------------------
// Score GEMM: 128p x 128c per block, split-bf16 3-MFMA, fused top-2.
// A staged as raw fp32 via gld16 (permuted slots), split in-register.
// Double-buffered LDS + raw vmcnt(8)/s_barrier pipeline.
// ---------------------------------------------------------------------------
__global__ __launch_bounds__(256) void score_kernel(
    const float* __restrict__ x, const uint32_t* __restrict__ ks,
    float2* __restrict__ pv2, uint32_t* __restrict__ pix) {

  __shared__ __align__(16) char lds[65536];
  // layout: A0 [0,16K) | A1 [16K,32K) | B0 [32K,48K) | B1 [48K,64K)

  const int ct = blockIdx.x, pt = blockIdx.y, b = blockIdx.z;
  const int tid  = threadIdx.x;
  const int lane = tid & 63, wave = tid >> 6;
  const int wr = wave >> 1, wc = wave & 1;

  // A staging global addresses: slot s = i*256+tid maps to
  // LDS byte s*16 = wr*8192 + fp*2048 + lane'*32 + h*16;
  // global row = wr*64+fp*16+lr', bytes kc*128 + kg'*32 + h*16.
  const char* xbase = (const char*)(x + ((size_t)b * PN + (size_t)pt * TP) * DD);
  const char* asrc[4];
#pragma unroll
  for (int i = 0; i < 4; i++) {
    int s = i * 256 + tid;
    int swr = s >> 9, sfp = (s >> 7) & 3, sl = (s >> 1) & 63, sh = s & 1;
    int row = swr * 64 + sfp * 16 + (sl & 15);
    asrc[i] = xbase + (size_t)row * (DD * 4) + (sl >> 4) * 32 + sh * 16;
  }
  const char* bsrc = (const char*)ks + ((size_t)ct * NKC) * 16384 + tid * 16;

  f32x4 acc[4][4];
#pragma unroll
  for (int i = 0; i < 4; i++)
#pragma unroll
    for (int j = 0; j < 4; j++) acc[i][j] = (f32x4)0.f;

  auto issue = [&](int kc) {
    char* Ab = lds + (kc & 1) * 16384;
    char* Bb = lds + 32768 + (kc & 1) * 16384;
#pragma unroll
    for (int i = 0; i < 4; i++)
      gld16(asrc[i] + kc * 128, Ab + i * 4096 + tid * 16);
#pragma unroll
    for (int i = 0; i < 4; i++)
      gld16(bsrc + kc * 16384 + i * 4096, Bb + i * 4096 + tid * 16);
  };

  issue(0);
  for (int kc = 0; kc < NKC; kc++) {
    if (kc + 1 < NKC) issue(kc + 1);       // prefetch stays in flight
    MEMFENCE();
    if (kc + 1 < NKC) {                    // wave-uniform; constant immediates
      __builtin_amdgcn_s_waitcnt(WAITCNT_VM8);
    } else {
      __builtin_amdgcn_s_waitcnt(WAITCNT_VM0);
    }
    __builtin_amdgcn_s_barrier();          // all waves' chunk-kc loads landed
    MEMFENCE();

    const char* Ab = lds + (kc & 1) * 16384;
    const char* Bb = lds + 32768 + (kc & 1) * 16384;

    bf16x8 Ah[4], Al[4];
#pragma unroll
    for (int fp = 0; fp < 4; fp++) {
      const float4* ap = (const float4*)(Ab + wr * 8192 + fp * 2048 + lane * 32);
      float4 v0 = ap[0], v1 = ap[1];
      uint2 h0, l0, h1, l1; split4(v0, h0, l0); split4(v1, h1, l1);
      uint4 hh = make_uint4(h0.x, h0.y, h1.x, h1.y);
      uint4 ll = make_uint4(l0.x, l0.y, l1.x, l1.y);
      Ah[fp] = *(bf16x8*)&hh;
      Al[fp] = *(bf16x8*)&ll;
    }
#pragma unroll
    for (int fc = 0; fc < 4; fc++) {
      const char* bp = Bb + wc * 4096 + fc * 1024 + lane * 16;
      bf16x8 Bh = *(const bf16x8*)bp;
      bf16x8 Bl = *(const bf16x8*)(bp + 8192);
#pragma unroll
      for (int fp = 0; fp < 4; fp++) {
        acc[fp][fc] = __builtin_amdgcn_mfma_f32_16x16x32_bf16(Ah[fp], Bh, acc[fp][fc], 0, 0, 0);
        acc[fp][fc] = __builtin_amdgcn_mfma_f32_16x16x32_bf16(Ah[fp], Bl, acc[fp][fc], 0, 0, 0);
        acc[fp][fc] = __builtin_amdgcn_mfma_f32_16x16x32_bf16(Al[fp], Bh, acc[fp][fc], 0, 0, 0);
      }
    }
    MEMFENCE();
    __builtin_amdgcn_s_barrier();          // readers done before buf reuse
    MEMFENCE();
  }
  __syncthreads();

  // relu + per-lane top2 per column (C layout: col=lane&15, row=kg*4+reg)
  const int lr = lane & 15, kg = lane >> 4;
  float4* scratch = (float4*)lds;          // reuse: [slot 0..7][col 0..127]
  const int slot = wr * 4 + kg;
#pragma unroll
  for (int fc = 0; fc < 4; fc++) {
    Top2 t; t.v1 = -1.f; t.v2 = -1.f; t.i1 = 0x7fffffff; t.i2 = 0x7fffffff;
#pragma unroll
    for (int fp = 0; fp < 4; fp++)
#pragma unroll
      for (int r = 0; r < 4; r++) {
        float v = acc[fp][fc][r]; v = v > 0.f ? v : 0.f;
        t2_insert(t, v, wr * 64 + fp * 16 + kg * 4 + r);
      }
    int c_local = wc * 64 + fc * 16 + lr;
    scratch[slot * TC + c_local] =
        make_float4(t.v1, __int_as_float(t.i1), t.v2, __int_as_float(t.i2));
  }
  __syncthreads();

  if (tid < TC) {
    Top2 t; t.v1 = -1.f; t.v2 = -1.f; t.i1 = 0x7fffffff; t.i2 = 0x7fffffff;
#pragma unroll
    for (int s = 0; s < 8; s++) {
      float4 e = scratch[s * TC + tid];
      t2_insert(t, e.x, __float_as_int(e.y));
      t2_insert(t, e.z, __float_as_int(e.w));
    }
    int c = ct * TC + tid;
    size_t o = ((size_t)b * CC + c) * NPT + pt;
    uint32_t p1 = (uint32_t)(pt * TP + t.i1);
    uint32_t p2 = (uint32_t)(pt * TP + t.i2);
    pv2[o] = make_float2(t.v1, t.v2);
    pix[o] = (p1 << 16) | (p2 & 0xffffu);
  }
}

// ---------------------------------------------------------------------------
// Per-(b,c): merge 32 tile top-2s; eps-guarded winner; exact fp32 rescue of
// near-ties. Writes winner[b][c] only.
// ---------------------------------------------------------------------------
__global__ __launch_bounds__(64) void reduce_winner_kernel(
    const float2* __restrict__ pv2, const uint32_t* __restrict__ pix,
    const float* __restrict__ x, const float* __restrict__ kern,
    int* __restrict__ winner) {
  const int c = blockIdx.x, b = blockIdx.y;
  const int l = threadIdx.x;

  Top2 t; t.v1 = -1.f; t.v2 = -1.f; t.i1 = 0x7fffffff; t.i2 = 0x7fffffff;
  if (l < NPT) {
    size_t o = ((size_t)b * CC + c) * NPT + l;
    float2 v = pv2[o]; uint32_t ii = pix[o];
    t.v1 = v.x; t.v2 = v.y; t.i1 = (int)(ii >> 16); t.i2 = (int)(ii & 0xffffu);
  }
#pragma unroll
  for (int m = 1; m < 64; m <<= 1) {
    float uv1 = __shfl_xor(t.v1, m, 64);
    int   ui1 = __shfl_xor(t.i1, m, 64);
    float uv2 = __shfl_xor(t.v2, m, 64);
    int   ui2 = __shfl_xor(t.i2, m, 64);
    t2_insert(t, uv1, ui1);
    t2_insert(t, uv2, ui2);
  }

  int win = t.i1;
  if (t.v1 - t.v2 <= 1e-4f * t.v1 + 1e-5f) {   // rare near-tie: exact fp32
    const float4* x1 = (const float4*)(x + ((size_t)b * PN + t.i1) * DD);
    const float4* x2 = (const float4*)(x + ((size_t)b * PN + t.i2) * DD);
    const float4* kc = (const float4*)(kern + (size_t)c * DD);
    float4 a1 = x1[l], a2 = x2[l], k4 = kc[l];
    float s1 = a1.x * k4.x + a1.y * k4.y + a1.z * k4.z + a1.w * k4.w;
    float s2 = a2.x * k4.x + a2.y * k4.y + a2.z * k4.z + a2.w * k4.w;
#pragma unroll
    for (int m = 1; m < 64; m <<= 1) {
      s1 += __shfl_xor(s1, m, 64);
      s2 += __shfl_xor(s2, m, 64);
    }
    s1 = fmaxf(s1, 0.f); s2 = fmaxf(s2, 0.f);
    if (s2 > s1 || (s2 == s1 && t.i2 < t.i1)) win = t.i2;
  }
  if (l == 0) winner[(size_t)b * CC + c] = win;
}

// ---------------------------------------------------------------------------
// 4 positions per block (4 waves); winner row staged in LDS once per block.
// Each wave ballots matching channels, sums kernel rows, writes its row.
// Full coverage -> no memset, no atomics.
// ---------------------------------------------------------------------------
__global__ __launch_bounds__(256) void write_out_kernel(
    const int* __restrict__ winner, const float* __restrict__ kern,
    float4* __restrict__ out) {
  __shared__ __align__(16) int wrow[CC];
  const int b = blockIdx.y;
  const int tid = threadIdx.x, lane = tid & 63, w = tid >> 6;
  const int p = blockIdx.x * 4 + w;

  *(int2*)&wrow[tid * 2] = *(const int2*)&winner[(size_t)b * CC + tid * 2];
  __syncthreads();

  int4 w0 = *(const int4*)&wrow[lane * 8];
  int4 w1 = *(const int4*)&wrow[lane * 8 + 4];
  int wv[8] = {w0.x, w0.y, w0.z, w0.w, w1.x, w1.y, w1.z, w1.w};

  float4 acc = make_float4(0.f, 0.f, 0.f, 0.f);
#pragma unroll
  for (int j = 0; j < 8; j++) {
    unsigned long long m = __ballot(wv[j] == p);
    while (m) {
      int bit = __ffsll((long long)m) - 1; m &= m - 1;
      int c = bit * 8 + j;                      // wave-uniform
      float4 kv = ((const float4*)(kern + (size_t)c * DD))[lane];
      acc.x += kv.x; acc.y += kv.y; acc.z += kv.z; acc.w += kv.w;
    }
  }
  out[((size_t)b * PN + p) * 64 + lane] = acc;
}

// ---------------------------------------------------------------------------
extern "C" void kernel_launch(void* const* d_in, const int* in_sizes, int n_in,
                              void* d_out, int out_size, void* d_ws, size_t ws_size,
                              hipStream_t stream) {
  const float* x    = (const float*)d_in[0];   // (16,4096,256)
  const float* kern = (const float*)d_in[1];   // (512,256)
  float* out = (float*)d_out;

  // ws: pv2 2 MB | pix 1 MB | ks 512 KB | winner 32 KB
  char* ws = (char*)d_ws;
  float2*   pv2 = (float2*)ws;
  uint32_t* pix = (uint32_t*)(ws + (size_t)BSZ * CC * NPT * sizeof(float2));
  uint32_t* ks  = (uint32_t*)(ws + 3u * 1024 * 1024);
  int*      win = (int*)(ws + 3u * 1024 * 1024 + 512u * 1024);

  convert_k_kernel<<<dim3(NKC, CC / TC), 256, 0, stream>>>(kern, ks);

  score_kernel<<<dim3(CC / TC, NPT, BSZ), 256, 0, stream>>>(x, ks, pv2, pix);

  reduce_winner_kernel<<<dim3(CC, BSZ), 64, 0, stream>>>(pv2, pix, x, kern, win);

  write_out_kernel<<<dim3(PN / 4, BSZ), 256, 0, stream>>>(win, kern, (float4*)out);
}